// Round 6
// baseline (193.983 us; speedup 1.0000x reference)
//
#include <hip/hip_runtime.h>

#define EMB 512
#define HEADS 8
#define HD 64
#define NSEQ 4096
#define BATCH 2
#define WINDOW 128

typedef unsigned short u16;
typedef __attribute__((ext_vector_type(8))) short bf16x8;
typedef __attribute__((ext_vector_type(4))) float f32x4;

__device__ __forceinline__ float bf2f(u16 u) {
    union { unsigned int i; float f; } x;
    x.i = ((unsigned int)u) << 16;
    return x.f;
}

__device__ __forceinline__ u16 f2bf(float f) {
    union { float f; unsigned int i; } x;
    x.f = f;
    unsigned int i = x.i;
    unsigned int lsb = (i >> 16) & 1u;
    i += 0x7fffu + lsb;   // round-to-nearest-even
    return (u16)(i >> 16);
}

struct raw8 { uint4 lo, hi; };   // bf16: lo only; fp32: lo+hi

__device__ __forceinline__ raw8 loadraw8(const void* base, size_t off, int isbf) {
    raw8 r;
    if (isbf) {
        r.lo = *(const uint4*)((const u16*)base + off);
    } else {
        const float* f = (const float*)base + off;
        r.lo = *(const uint4*)f;
        r.hi = *(const uint4*)(f + 4);
    }
    return r;
}

__device__ __forceinline__ uint4 cvt8(const raw8& r, int isbf) {
    if (isbf) return r.lo;
    const float* a = (const float*)&r.lo;
    const float* b = (const float*)&r.hi;
    uint4 o;
    o.x = (unsigned)f2bf(a[0]) | ((unsigned)f2bf(a[1]) << 16);
    o.y = (unsigned)f2bf(a[2]) | ((unsigned)f2bf(a[3]) << 16);
    o.z = (unsigned)f2bf(b[0]) | ((unsigned)f2bf(b[1]) << 16);
    o.w = (unsigned)f2bf(b[2]) | ((unsigned)f2bf(b[3]) << 16);
    return o;
}

__device__ __forceinline__ float loadScalar(const void* base, int i, int isbf) {
    return isbf ? bf2f(((const u16*)base)[i]) : ((const float*)base)[i];
}

__device__ __forceinline__ int probe_bf16(const void* p) {
    const int lane = threadIdx.x & 63;
    u16 w = ((const u16*)p)[lane * 2];
    int e = (w >> 7) & 0xff;
    bool sane = (w == 0) || (e >= 100 && e <= 140);
    unsigned long long m = __ballot(sane);
    return __popcll(m) >= 48;
}

// ---------------------------------------------------------------------------
// Fused QKV projection. q,k -> [bh][n][64]; v -> TRANSPOSED [bh][d][n] (for
// attn's PV B-frags). q pre-scaled by 1/sqrt(512). grid (64, 12).
// LDS double-buffer (1 barrier/iter), fragment-linear layout (0 conflicts):
//   element A[m=I*16+l16][k=quad*8+j] lives at u16 addr I*512 + lane*8 + j.
// ---------------------------------------------------------------------------
__global__ __launch_bounds__(256)
void qkv_gemm(const void* __restrict__ X,
              const void* __restrict__ Wq, const void* __restrict__ bq,
              const void* __restrict__ Wk, const void* __restrict__ bk,
              const void* __restrict__ Wv, const void* __restrict__ bv,
              u16* __restrict__ qo, u16* __restrict__ ko, u16* __restrict__ vo,
              int* __restrict__ flags)
{
    __shared__ __align__(16) u16 As[2][128 * 32];
    __shared__ __align__(16) u16 Bs[2][128 * 32];

    const int tid  = threadIdx.x;
    const int wave = tid >> 6;
    const int lane = tid & 63;
    const int quad = lane >> 4;
    const int l16  = lane & 15;
    const int wm = wave >> 1, wn = wave & 1;

    const int m0 = blockIdx.x * 128;
    const int by = blockIdx.y;
    const int wsel = by >> 2;
    const int n0 = (by & 3) * 128;

    const void* W  = (wsel == 0) ? Wq : (wsel == 1) ? Wk : Wv;
    const void* bi = (wsel == 0) ? bq : (wsel == 1) ? bk : bv;
    u16* out       = (wsel == 0) ? qo : (wsel == 1) ? ko : vo;
    const float oscale = (wsel == 0) ? 0.04419417382415922f : 1.0f;

    const int fx = probe_bf16(X);
    const int fw = probe_bf16(W);
    const int fb = probe_bf16(bi);
    if (blockIdx.x == 0 && by == 0 && tid == 0) flags[0] = fx;

    f32x4 acc[4][4];
#pragma unroll
    for (int i = 0; i < 4; ++i)
#pragma unroll
        for (int j = 0; j < 4; ++j)
            acc[i][j] = (f32x4){0.f, 0.f, 0.f, 0.f};

    // write-linear staging map: thread (wave,lane), s=0/1 -> I = wave+4s,
    // global row = I*16 + (lane&15), k-chunk = lane>>4, LDS dest = I*512+lane*8
    const int r1 = wave * 16 + l16, r2 = r1 + 64;
    const int cc = (lane >> 4) * 8;
    const int d1 = wave * 512 + lane * 8, d2 = d1 + 2048;

    // tile 0: load + store
    raw8 a1 = loadraw8(X, (size_t)(m0 + r1) * EMB + cc, fx);
    raw8 a2 = loadraw8(X, (size_t)(m0 + r2) * EMB + cc, fx);
    raw8 b1 = loadraw8(W, (size_t)(n0 + r1) * EMB + cc, fw);
    raw8 b2 = loadraw8(W, (size_t)(n0 + r2) * EMB + cc, fw);
    *(uint4*)&As[0][d1] = cvt8(a1, fx);
    *(uint4*)&As[0][d2] = cvt8(a2, fx);
    *(uint4*)&Bs[0][d1] = cvt8(b1, fw);
    *(uint4*)&Bs[0][d2] = cvt8(b2, fw);
    // prefetch tile 1
    a1 = loadraw8(X, (size_t)(m0 + r1) * EMB + 32 + cc, fx);
    a2 = loadraw8(X, (size_t)(m0 + r2) * EMB + 32 + cc, fx);
    b1 = loadraw8(W, (size_t)(n0 + r1) * EMB + 32 + cc, fw);
    b2 = loadraw8(W, (size_t)(n0 + r2) * EMB + 32 + cc, fw);
    __syncthreads();

    for (int kt = 0; kt < 16; ++kt) {
        const int buf = kt & 1;
        bf16x8 af[4], bfr[4];
#pragma unroll
        for (int i = 0; i < 4; ++i)
            af[i] = *(const bf16x8*)&As[buf][(wm * 4 + i) * 512 + lane * 8];
#pragma unroll
        for (int j = 0; j < 4; ++j)
            bfr[j] = *(const bf16x8*)&Bs[buf][(wn * 4 + j) * 512 + lane * 8];

        if (kt < 15) {                       // store prefetched tile kt+1 into idle buffer
            const int nb = buf ^ 1;
            *(uint4*)&As[nb][d1] = cvt8(a1, fx);
            *(uint4*)&As[nb][d2] = cvt8(a2, fx);
            *(uint4*)&Bs[nb][d1] = cvt8(b1, fw);
            *(uint4*)&Bs[nb][d2] = cvt8(b2, fw);
            if (kt < 14) {                   // issue loads for tile kt+2
                const int kk0 = (kt + 2) * 32;
                a1 = loadraw8(X, (size_t)(m0 + r1) * EMB + kk0 + cc, fx);
                a2 = loadraw8(X, (size_t)(m0 + r2) * EMB + kk0 + cc, fx);
                b1 = loadraw8(W, (size_t)(n0 + r1) * EMB + kk0 + cc, fw);
                b2 = loadraw8(W, (size_t)(n0 + r2) * EMB + kk0 + cc, fw);
            }
        }

#pragma unroll
        for (int i = 0; i < 4; ++i)
#pragma unroll
            for (int j = 0; j < 4; ++j)
                acc[i][j] = __builtin_amdgcn_mfma_f32_16x16x32_bf16(af[i], bfr[j], acc[i][j], 0, 0, 0);
        __syncthreads();
    }

    // epilogue: q/k -> [bh][n][d]; v -> [bh][d][n] (transposed)
#pragma unroll
    for (int j = 0; j < 4; ++j) {
        const int col = n0 + wn * 64 + j * 16 + l16;
        const float bv_ = loadScalar(bi, col, fb);
        const int h = col >> 6, d = col & 63;
#pragma unroll
        for (int i = 0; i < 4; ++i) {
#pragma unroll
            for (int r = 0; r < 4; ++r) {
                const int row = m0 + wm * 64 + i * 16 + quad * 4 + r;
                const int b = row >> 12, n = row & 4095;
                const u16 val = f2bf((acc[i][j][r] + bv_) * oscale);
                if (wsel == 2)
                    out[((size_t)((b * HEADS + h) * HD + d)) * NSEQ + n] = val;
                else
                    out[(((size_t)(b * HEADS + h) * NSEQ) + n) * HD + d] = val;
            }
        }
    }
}

// ---------------------------------------------------------------------------
// MFMA flash attention. q,k: [bh][n][64]; v: [bh][d][n] (pre-transposed).
// Block = 4 waves = 64 queries of one (b,h); 5 chunks of 64 keys. grid (64,16).
// ---------------------------------------------------------------------------
#define KP 72
__global__ __launch_bounds__(256)
void attn_mfma(const u16* __restrict__ q, const u16* __restrict__ k,
               const u16* __restrict__ v, u16* __restrict__ ao)
{
    __shared__ __align__(16) u16 Ks[64 * KP];      // [key][d]
    __shared__ __align__(16) u16 Vt[64 * KP];      // [d][key]  (direct from v)
    __shared__ __align__(16) u16 Pb[4][16 * KP];   // per-wave P [q][key]

    const int tid  = threadIdx.x;
    const int wave = tid >> 6;
    const int lane = tid & 63;
    const int quad = lane >> 4;
    const int l16  = lane & 15;

    const int bh = blockIdx.y;
    const int q0 = blockIdx.x * 64;
    const int qw = q0 + wave * 16;
    const size_t base = (size_t)bh * NSEQ * HD;    // same for q,k ([n][d]) and v ([d][n])

    bf16x8 qa0 = *(const bf16x8*)(q + base + (size_t)(qw + l16) * HD + quad * 8);
    bf16x8 qa1 = *(const bf16x8*)(q + base + (size_t)(qw + l16) * HD + 32 + quad * 8);

    f32x4 O[4];
    float m_run[4], l_run[4];
#pragma unroll
    for (int t = 0; t < 4; ++t) O[t] = (f32x4){0.f, 0.f, 0.f, 0.f};
#pragma unroll
    for (int r = 0; r < 4; ++r) { m_run[r] = -1e30f; l_run[r] = 0.f; }

    // staging geometry: K: key=idx>>3, d-chunk=(idx&7)*8 ; V: d=idx>>3, key-chunk=(idx&7)*8
    const int row_s[2] = { tid >> 3, (tid + 256) >> 3 };
    const int ch8      = (tid & 7) * 8;

    uint4 pkv[2], pvv[2];
    {
        const int kbase = q0 - 128;
        const int koff  = (kbase < 0) ? 0 : (kbase > NSEQ - 64 ? NSEQ - 64 : kbase);
#pragma unroll
        for (int s = 0; s < 2; ++s) {
            int kg = kbase + row_s[s];
            kg = (kg < 0) ? 0 : (kg > NSEQ - 1 ? NSEQ - 1 : kg);
            pkv[s] = *(const uint4*)(k + base + (size_t)kg * HD + ch8);
            pvv[s] = *(const uint4*)(v + base + (size_t)row_s[s] * NSEQ + koff + ch8);
        }
    }

    for (int c = 0; c < 5; ++c) {
        const int kbase = q0 - 128 + c * 64;

        __syncthreads();
#pragma unroll
        for (int s = 0; s < 2; ++s) {
            *(uint4*)&Ks[row_s[s] * KP + ch8] = pkv[s];
            *(uint4*)&Vt[row_s[s] * KP + ch8] = pvv[s];
        }
        __syncthreads();

        if (c < 4) {   // prefetch next chunk
            const int kb2  = kbase + 64;
            const int koff = (kb2 < 0) ? 0 : (kb2 > NSEQ - 64 ? NSEQ - 64 : kb2);
#pragma unroll
            for (int s = 0; s < 2; ++s) {
                int kg = kb2 + row_s[s];
                kg = (kg < 0) ? 0 : (kg > NSEQ - 1 ? NSEQ - 1 : kg);
                pkv[s] = *(const uint4*)(k + base + (size_t)kg * HD + ch8);
                pvv[s] = *(const uint4*)(v + base + (size_t)row_s[s] * NSEQ + koff + ch8);
            }
        }

        // ---- QK^T ----
        f32x4 sv[4];
#pragma unroll
        for (int t = 0; t < 4; ++t) {
            bf16x8 b0 = *(const bf16x8*)&Ks[(t * 16 + l16) * KP + quad * 8];
            bf16x8 b1 = *(const bf16x8*)&Ks[(t * 16 + l16) * KP + 32 + quad * 8];
            f32x4 sacc = (f32x4){0.f, 0.f, 0.f, 0.f};
            sacc = __builtin_amdgcn_mfma_f32_16x16x32_bf16(qa0, b0, sacc, 0, 0, 0);
            sacc = __builtin_amdgcn_mfma_f32_16x16x32_bf16(qa1, b1, sacc, 0, 0, 0);
            sv[t] = sacc;
        }

        // ---- band mask (kills OOB + clamped-garbage columns) ----
#pragma unroll
        for (int t = 0; t < 4; ++t) {
            const int jg = kbase + t * 16 + l16;
            const bool jok = ((unsigned)jg) < (unsigned)NSEQ;
#pragma unroll
            for (int r = 0; r < 4; ++r) {
                const int iq = qw + quad * 4 + r;
                const bool band = ((unsigned)(iq - jg + WINDOW)) <= (unsigned)(2 * WINDOW);
                if (!(jok && band)) sv[t][r] = -1e30f;
            }
        }

        // ---- online softmax ----
        float mnew[4];
#pragma unroll
        for (int r = 0; r < 4; ++r)
            mnew[r] = fmaxf(fmaxf(sv[0][r], sv[1][r]), fmaxf(sv[2][r], sv[3][r]));
#pragma unroll
        for (int off = 1; off < 16; off <<= 1)
#pragma unroll
            for (int r = 0; r < 4; ++r)
                mnew[r] = fmaxf(mnew[r], __shfl_xor(mnew[r], off, 64));

        float alpha[4], mi[4];
#pragma unroll
        for (int r = 0; r < 4; ++r) {
            mi[r] = fmaxf(m_run[r], mnew[r]);
            alpha[r] = __expf(m_run[r] - mi[r]);
            m_run[r] = mi[r];
        }

        float p[4][4], lnew[4] = {0.f, 0.f, 0.f, 0.f};
#pragma unroll
        for (int t = 0; t < 4; ++t)
#pragma unroll
            for (int r = 0; r < 4; ++r) {
                float pv = (sv[t][r] > -1e29f) ? __expf(sv[t][r] - mi[r]) : 0.f;
                p[t][r] = pv;
                lnew[r] += pv;
            }
#pragma unroll
        for (int off = 1; off < 16; off <<= 1)
#pragma unroll
            for (int r = 0; r < 4; ++r)
                lnew[r] += __shfl_xor(lnew[r], off, 64);
#pragma unroll
        for (int r = 0; r < 4; ++r)
            l_run[r] = l_run[r] * alpha[r] + lnew[r];

#pragma unroll
        for (int t = 0; t < 4; ++t)
#pragma unroll
            for (int r = 0; r < 4; ++r)
                O[t][r] *= alpha[r];

        // ---- P -> LDS (C-layout), read back A-layout (same-wave dep) ----
#pragma unroll
        for (int t = 0; t < 4; ++t)
#pragma unroll
            for (int r = 0; r < 4; ++r)
                Pb[wave][(quad * 4 + r) * KP + t * 16 + l16] = f2bf(p[t][r]);

        // ---- PV ----
#pragma unroll
        for (int ks = 0; ks < 2; ++ks) {
            bf16x8 pa = *(const bf16x8*)&Pb[wave][l16 * KP + ks * 32 + quad * 8];
#pragma unroll
            for (int t = 0; t < 4; ++t) {
                bf16x8 vb = *(const bf16x8*)&Vt[(t * 16 + l16) * KP + ks * 32 + quad * 8];
                O[t] = __builtin_amdgcn_mfma_f32_16x16x32_bf16(pa, vb, O[t], 0, 0, 0);
            }
        }
    }

    const int bb = bh >> 3, hh = bh & 7;
    float rl[4];
#pragma unroll
    for (int r = 0; r < 4; ++r) rl[r] = 1.f / l_run[r];
#pragma unroll
    for (int t = 0; t < 4; ++t)
#pragma unroll
        for (int r = 0; r < 4; ++r) {
            const int iq = qw + quad * 4 + r;
            ao[((size_t)(bb * NSEQ + iq)) * EMB + hh * HD + t * 16 + l16] =
                f2bf(O[t][r] * rl[r]);
        }
}

// ---------------------------------------------------------------------------
// Output projection: out = ao @ Wo.T + bo. Same dbuf/fragment-linear structure.
// grid (64, 4).
// ---------------------------------------------------------------------------
__global__ __launch_bounds__(256)
void out_gemm(const u16* __restrict__ A, const void* __restrict__ W,
              const void* __restrict__ bias, void* __restrict__ out,
              const int* __restrict__ flags)
{
    __shared__ __align__(16) u16 As[2][128 * 32];
    __shared__ __align__(16) u16 Bs[2][128 * 32];

    const int tid  = threadIdx.x;
    const int wave = tid >> 6;
    const int lane = tid & 63;
    const int quad = lane >> 4;
    const int l16  = lane & 15;
    const int wm = wave >> 1, wn = wave & 1;

    const int m0 = blockIdx.x * 128;
    const int n0 = blockIdx.y * 128;

    const int fw = probe_bf16(W);
    const int fb = probe_bf16(bias);
    const int fo = flags[0];

    f32x4 acc[4][4];
#pragma unroll
    for (int i = 0; i < 4; ++i)
#pragma unroll
        for (int j = 0; j < 4; ++j)
            acc[i][j] = (f32x4){0.f, 0.f, 0.f, 0.f};

    const int r1 = wave * 16 + l16, r2 = r1 + 64;
    const int cc = (lane >> 4) * 8;
    const int d1 = wave * 512 + lane * 8, d2 = d1 + 2048;

    raw8 a1 = loadraw8(A, (size_t)(m0 + r1) * EMB + cc, 1);
    raw8 a2 = loadraw8(A, (size_t)(m0 + r2) * EMB + cc, 1);
    raw8 b1 = loadraw8(W, (size_t)(n0 + r1) * EMB + cc, fw);
    raw8 b2 = loadraw8(W, (size_t)(n0 + r2) * EMB + cc, fw);
    *(uint4*)&As[0][d1] = a1.lo;
    *(uint4*)&As[0][d2] = a2.lo;
    *(uint4*)&Bs[0][d1] = cvt8(b1, fw);
    *(uint4*)&Bs[0][d2] = cvt8(b2, fw);
    a1 = loadraw8(A, (size_t)(m0 + r1) * EMB + 32 + cc, 1);
    a2 = loadraw8(A, (size_t)(m0 + r2) * EMB + 32 + cc, 1);
    b1 = loadraw8(W, (size_t)(n0 + r1) * EMB + 32 + cc, fw);
    b2 = loadraw8(W, (size_t)(n0 + r2) * EMB + 32 + cc, fw);
    __syncthreads();

    for (int kt = 0; kt < 16; ++kt) {
        const int buf = kt & 1;
        bf16x8 af[4], bfr[4];
#pragma unroll
        for (int i = 0; i < 4; ++i)
            af[i] = *(const bf16x8*)&As[buf][(wm * 4 + i) * 512 + lane * 8];
#pragma unroll
        for (int j = 0; j < 4; ++j)
            bfr[j] = *(const bf16x8*)&Bs[buf][(wn * 4 + j) * 512 + lane * 8];

        if (kt < 15) {
            const int nb = buf ^ 1;
            *(uint4*)&As[nb][d1] = a1.lo;
            *(uint4*)&As[nb][d2] = a2.lo;
            *(uint4*)&Bs[nb][d1] = cvt8(b1, fw);
            *(uint4*)&Bs[nb][d2] = cvt8(b2, fw);
            if (kt < 14) {
                const int kk0 = (kt + 2) * 32;
                a1 = loadraw8(A, (size_t)(m0 + r1) * EMB + kk0 + cc, 1);
                a2 = loadraw8(A, (size_t)(m0 + r2) * EMB + kk0 + cc, 1);
                b1 = loadraw8(W, (size_t)(n0 + r1) * EMB + kk0 + cc, fw);
                b2 = loadraw8(W, (size_t)(n0 + r2) * EMB + kk0 + cc, fw);
            }
        }

#pragma unroll
        for (int i = 0; i < 4; ++i)
#pragma unroll
            for (int j = 0; j < 4; ++j)
                acc[i][j] = __builtin_amdgcn_mfma_f32_16x16x32_bf16(af[i], bfr[j], acc[i][j], 0, 0, 0);
        __syncthreads();
    }

#pragma unroll
    for (int j = 0; j < 4; ++j) {
        const int col = n0 + wn * 64 + j * 16 + l16;
        const float bv_ = loadScalar(bias, col, fb);
#pragma unroll
        for (int i = 0; i < 4; ++i) {
#pragma unroll
            for (int r = 0; r < 4; ++r) {
                const int row = m0 + wm * 64 + i * 16 + quad * 4 + r;
                const float val = acc[i][j][r] + bv_;
                const size_t idx = (size_t)row * EMB + col;
                if (fo) ((u16*)out)[idx] = f2bf(val);
                else    ((float*)out)[idx] = val;
            }
        }
    }
}

extern "C" void kernel_launch(void* const* d_in, const int* in_sizes, int n_in,
                              void* d_out, int out_size, void* d_ws, size_t ws_size,
                              hipStream_t stream)
{
    const size_t HSZ  = (size_t)BATCH * HEADS * NSEQ * HD;   // 4.19M elems
    const size_t HSZB = HSZ * 2;                             // 8.39 MB
    char* base = (char*)d_ws;
    int* flags = (int*)base;
    const size_t off = 256;

    u16 *q, *k, *v, *ao;
    if (ws_size >= off + 4 * HSZB) {
        q  = (u16*)(base + off);
        k  = q + HSZ;
        v  = k + HSZ;
        ao = v + HSZ;
    } else if (ws_size >= off + 3 * HSZB) {
        q  = (u16*)d_out;            // dead before out_gemm writes d_out
        k  = (u16*)(base + off);
        v  = k + HSZ;
        ao = v + HSZ;
    } else {
        q  = (u16*)d_out;
        k  = (u16*)(base + off);
        v  = k + HSZ;
        ao = (u16*)d_in[0];          // x dead after qkv_gemm; restored each launch
    }

    qkv_gemm<<<dim3(64, 12), 256, 0, stream>>>(d_in[0], d_in[1], d_in[2], d_in[3],
                                               d_in[4], d_in[5], d_in[6], q, k, v, flags);
    attn_mfma<<<dim3(64, 16), 256, 0, stream>>>(q, k, v, ao);
    out_gemm<<<dim3(64, 4), 256, 0, stream>>>(ao, d_in[7], d_in[8], d_out, flags);
}